// Round 17
// baseline (1974.508 us; speedup 1.0000x reference)
//
#include <hip/hip_runtime.h>
#include <stdint.h>
#include <stddef.h>

typedef __attribute__((ext_vector_type(8))) _Float16 half8;
typedef __attribute__((ext_vector_type(8))) unsigned short ushort8;
typedef __attribute__((ext_vector_type(4))) float f4;
typedef __attribute__((ext_vector_type(2))) float f2;

#define AS1 __attribute__((address_space(1)))
#define AS3 __attribute__((address_space(3)))

namespace {
constexpr int kSteps = 255;   // reference iterates t = 0 .. T-2
constexpr int KTOT = 1152;    // 1024 (h) + 128 (x)

// workspace layout (bytes); total ~45 MB
// h layout: [group(16)][ub(32)][row(32)][u(32)] fp16 -> 2KB block slices
constexpr size_t OFF_H0   = 0;                                   // 1 MB  h ping
constexpr size_t OFF_CNT  = (size_t)1 << 20;                     // 4 KB  counters (16 x 64B)
constexpr size_t OFF_H1   = ((size_t)1 << 20) + 4096;            // 1 MB  h pong
constexpr size_t OFF_BSUM = OFF_H1 + ((size_t)1 << 20);          // 16 KB b_ih+b_hh (fp32)
constexpr size_t OFF_WCAT = OFF_BSUM + 16384;                    // 9.4 MB fp16 [4096][1152]
constexpr size_t OFF_XT   = OFF_WCAT + (size_t)4096 * KTOT * 2;  // 33.4 MB fp16 [255][512][128]
}

__device__ __forceinline__ unsigned short f2h(float f) {
  _Float16 h = (_Float16)f;
  return __builtin_bit_cast(unsigned short, h);
}
__device__ __forceinline__ float h2f(unsigned short s) {
  return (float)__builtin_bit_cast(_Float16, s);
}

// ---------- prep 1: Wcat fp16 + bsum ----------
__global__ void prep_wcat(const float* __restrict__ Wih, const float* __restrict__ Whh,
                          const float* __restrict__ bih, const float* __restrict__ bhh,
                          char* __restrict__ ws) {
  if (blockIdx.x < 2304) {
    unsigned gid = blockIdx.x * 256 + threadIdx.x;
    unsigned row = gid / 144, cc = gid % 144;
    const float* src = (cc < 128) ? (Whh + (size_t)row * 1024 + (size_t)cc * 8)
                                  : (Wih + (size_t)row * 128 + (size_t)(cc - 128) * 8);
    ushort8 o;
#pragma unroll
    for (int j = 0; j < 8; j++) o[j] = f2h(src[j]);
    *(ushort8*)((unsigned short*)(ws + OFF_WCAT) + (size_t)row * KTOT + cc * 8) = o;
  } else {
    int i = (blockIdx.x - 2304) * 256 + threadIdx.x;
    ((float*)(ws + OFF_BSUM))[i] = bih[i] + bhh[i];
  }
}

// ---------- prep 2: xT[t][b][i] = fp16(x[b][i][t]) ----------
__global__ void prep_xt(const float* __restrict__ x, char* __restrict__ ws) {
  unsigned short* xT = (unsigned short*)(ws + OFF_XT);
  __shared__ unsigned short tile[128][72];
  const int b = blockIdx.x >> 2;
  const int t0 = (blockIdx.x & 3) * 64;
  const int wv = threadIdx.x >> 6, tl = threadIdx.x & 63;
  if (t0 + tl < 255) {
#pragma unroll
    for (int ii = 0; ii < 32; ii++) {
      int i = wv + ii * 4;
      tile[i][tl] = f2h(x[((size_t)b * 128 + i) * 256 + t0 + tl]);
    }
  }
  __syncthreads();
  const int tl2 = threadIdx.x >> 4, ic = threadIdx.x & 15;
#pragma unroll
  for (int pp = 0; pp < 4; pp++) {
    int tloc = pp * 16 + tl2;
    int t = t0 + tloc;
    if (t < 255) {
      ushort8 v;
#pragma unroll
      for (int j = 0; j < 8; j++) v[j] = tile[ic * 8 + j][tloc];
      *(ushort8*)&xT[((size_t)t * 512 + b) * 128 + ic * 8] = v;
    }
  }
}

// ---------- persistent LSTM kernel: DUAL-CHAIN, cross-pipelined, piped spin ----------
// grid 256 = (bid&7) -> groups {g, g+8} (both on XCD g), bid>>3 -> 32-unit tile.
// Per iteration: [issue pollB] COMPUTE A (0 barriers) -> check pollB (latency hidden
// under compute) + sync -> STAGE ring B (flies under A's exchange) -> EXCH A ->
// same for B. Bias folded into the x-MFMA (C = bias4) -> no acc-init movs.
// Coherence (r8/r15-proven, no inv): h stores write-through sc0 sc1; h loads SC0;
// relaxed release after vmcnt(0) drain.
__global__ __launch_bounds__(512) __attribute__((amdgpu_waves_per_eu(2, 2)))
void lstm_persist(char* __restrict__ ws) {
  const unsigned short* __restrict__ wcat = (const unsigned short*)(ws + OFF_WCAT);
  const float* __restrict__ bsum = (const float*)(ws + OFF_BSUM);
  const unsigned short* __restrict__ xT = (const unsigned short*)(ws + OFF_XT);
  unsigned short* h0 = (unsigned short*)(ws + OFF_H0);
  unsigned short* h1 = (unsigned short*)(ws + OFF_H1);

  __shared__ __align__(16) char lds[131072];   // 2 rings x (8 bufs x 8KB); exchange reuses ring

  const int tid = threadIdx.x;
  const int lane = tid & 63;
  const int w = tid >> 6;
  const int wk = w & 3;           // K slice (32 cols of each 128-col chunk)
  const int wn = w >> 2;          // N half (64 of 128 gate cols)
  const int l15 = lane & 15, l4 = lane >> 4;
  const int gA = blockIdx.x & 7;       // chain A group (XCD-aligned)
  const int gB = gA + 8;               // chain B group (same XCD)
  const int cblk = blockIdx.x >> 3;    // unit tile 0..31
  const int U0 = cblk * 32;
  int* cntA = (int*)(ws + OFF_CNT) + gA * 16;
  int* cntB = (int*)(ws + OFF_CNT) + gB * 16;

  // ---- weight fragments -> registers. col n = wn*64+nf*16+l15 = unit*4+gate ----
  half8 bf[9][4];   // 144 regs, shared by both chains
  f4 bias4[4];      // bias-fold C operand (16 regs, persistent)
#pragma unroll
  for (int nf = 0; nf < 4; nf++) {
    int u = wn * 16 + nf * 4 + (l15 >> 2);
    int R = (l15 & 3) * 1024 + U0 + u;          // PyTorch gate order i,f,g,o
    float b = bsum[R];
    float bs = (wk == 0) ? b : 0.f;             // 4-way K reduce: one slice seeds bias
    bias4[nf] = (f4){bs, bs, bs, bs};
#pragma unroll
    for (int c = 0; c < 9; c++)
      bf[c][nf] = *(const half8*)&wcat[(size_t)R * KTOT + c * 128 + wk * 32 + l4 * 8];
  }

  // ---- staging: chunk 8KB = 8 slots of 1KB; slot = w (1 load/wave/chunk) ----
  // LDS (row, c16) holds G(row, c16 ^ (row&7)); source pre-inverse-swizzled (rule #21).
  const int srow = w * 4 + (lane >> 4);          // 0..31
  const int scg = (lane & 15) ^ (srow & 7);
  const int hoff1 = (scg >> 2) * 1024 + srow * 32 + (scg & 3) * 8;   // + c*4096 per chunk
  // A ds_read: row = m*16+l15, c16 = (wk*4+l4) ^ (l15&7); a1 at +4096 (m=1)
  const int aBase = l15 * 256 + (((wk * 4 + l4) ^ (l15 & 7)) * 16);
  const int xco = (wk * 4 + l4) * 8;             // x direct-to-reg column (halves)

  // exchange constants. writer: n = wn*64+nf*16+l15 (0..127), rf = m*4+l4 (0..7)
  int nb8[4], hnw[4];
#pragma unroll
  for (int nf = 0; nf < 4; nf++) {
    int n = wn * 64 + nf * 16 + l15;
    nb8[nf] = n * 8;
    hnw[nf] = (n ^ (n >> 3)) & 7;
  }
  // reader: thread owns (unit uu, rows qr*4+hi*2 .. +1); float2 reads per slice
  const int uu = tid & 31;
  const int qr = (tid >> 5) & 7;
  const int hi = (tid >> 8) & 1;
  int ro2[4];
#pragma unroll
  for (int g2 = 0; g2 < 4; g2++) {
    int n = 4 * uu + g2;
    ro2[g2] = (n * 8 + (qr ^ ((n ^ (n >> 3)) & 7))) * 16 + hi * 8;
  }
  const size_t hbA = ((size_t)(gA * 32 + cblk) * 32 + (qr * 4 + hi * 2)) * 32 + uu;
  const size_t hbB = ((size_t)(gB * 32 + cblk) * 32 + (qr * 4 + hi * 2)) * 32 + uu;

  f4 acc[2][4];
  half8 xa0, xa1, xb0, xb1;                     // x fragments (global->reg, no LDS)
  float cA0 = 0.f, cA1 = 0.f, cB0 = 0.f, cB1 = 0.f;
  int pollA = 0, pollB = 0;                     // pipelined counter polls (tid0)

#define STG(HS, C, RB, BUF) \
  __builtin_amdgcn_global_load_lds( \
      (const AS1 void*)((HS) + hoff1 + (C) * 4096), \
      (AS3 void*)(lds + (RB) + (BUF) * 8192 + w * 1024), 16, 0, 1)

#define STG_RING(HS, RB) do { \
    STG(HS, 0, RB, 0); STG(HS, 1, RB, 1); STG(HS, 2, RB, 2); STG(HS, 3, RB, 3); \
    STG(HS, 4, RB, 4); STG(HS, 5, RB, 5); STG(HS, 6, RB, 6); STG(HS, 7, RB, 7); \
  } while (0)

#define MFMA8(A0, A1, C) do { \
    acc[0][0] = __builtin_amdgcn_mfma_f32_16x16x32_f16(A0, bf[C][0], acc[0][0], 0, 0, 0); \
    acc[0][1] = __builtin_amdgcn_mfma_f32_16x16x32_f16(A0, bf[C][1], acc[0][1], 0, 0, 0); \
    acc[0][2] = __builtin_amdgcn_mfma_f32_16x16x32_f16(A0, bf[C][2], acc[0][2], 0, 0, 0); \
    acc[0][3] = __builtin_amdgcn_mfma_f32_16x16x32_f16(A0, bf[C][3], acc[0][3], 0, 0, 0); \
    acc[1][0] = __builtin_amdgcn_mfma_f32_16x16x32_f16(A1, bf[C][0], acc[1][0], 0, 0, 0); \
    acc[1][1] = __builtin_amdgcn_mfma_f32_16x16x32_f16(A1, bf[C][1], acc[1][1], 0, 0, 0); \
    acc[1][2] = __builtin_amdgcn_mfma_f32_16x16x32_f16(A1, bf[C][2], acc[1][2], 0, 0, 0); \
    acc[1][3] = __builtin_amdgcn_mfma_f32_16x16x32_f16(A1, bf[C][3], acc[1][3], 0, 0, 0); \
  } while (0)

#define CMP(C, RB) do { \
    const char* _b = lds + (RB) + (C) * 8192 + aBase; \
    half8 a0 = *(const half8*)(_b); \
    half8 a1 = *(const half8*)(_b + 4096); \
    MFMA8(a0, a1, C); \
  } while (0)

// first MFMA writes acc = x*Wx + bias (no acc-init movs)
#define COMPUTE_ALL(RB, XA0, XA1) do { \
    _Pragma("unroll") \
    for (int nf = 0; nf < 4; nf++) { \
      acc[0][nf] = __builtin_amdgcn_mfma_f32_16x16x32_f16(XA0, bf[8][nf], bias4[nf], 0, 0, 0); \
      acc[1][nf] = __builtin_amdgcn_mfma_f32_16x16x32_f16(XA1, bf[8][nf], bias4[nf], 0, 0, 0); \
    } \
    CMP(0, RB); CMP(1, RB); CMP(2, RB); CMP(3, RB); \
    CMP(4, RB); CMP(5, RB); CMP(6, RB); CMP(7, RB); \
  } while (0)

// issue the counter poll (tid0, non-blocking); check after compute
#define SPIN_ISSUE(PV, CNTP) do { \
    if (tid == 0) \
      asm volatile("global_load_dword %0, %1, off sc0 sc1" : "=v"(PV) : "v"(CNTP)); \
  } while (0)

#define SPIN_CHECK(PV, CNTP, TGT) do { \
    if (tid == 0) { \
      asm volatile("s_waitcnt vmcnt(0)" ::: "memory"); \
      int c = PV; \
      if (c < (TGT)) { \
        int guard = 1 << 18; \
        while (guard--) { \
          asm volatile("global_load_dword %0, %1, off sc0 sc1\n\ts_waitcnt vmcnt(0)" \
                       : "=v"(c) : "v"(CNTP) : "memory"); \
          if (c >= (TGT)) break; \
          __builtin_amdgcn_s_sleep(1); \
        } \
      } \
    } \
    __syncthreads(); /* joins; also = pre-exchange barrier (compute reads drained) */ \
  } while (0)

// exchange (in own ring) + activation + h store + release; 2 barriers
#define EXCHFIN(RB, HDST, HB, C0, C1, CNTP) do { \
    _Pragma("unroll") \
    for (int m = 0; m < 2; m++) \
      _Pragma("unroll") \
      for (int nf = 0; nf < 4; nf++) { \
        int rf = m * 4 + l4; \
        *(f4*)(lds + (RB) + wk * 16384 + (size_t)(nb8[nf] + (rf ^ hnw[nf])) * 16) = acc[m][nf]; \
      } \
    __syncthreads(); \
    { \
      f2 gsv[4]; \
      _Pragma("unroll") \
      for (int g2 = 0; g2 < 4; g2++) { \
        f2 s0 = *(const f2*)(lds + (RB) + ro2[g2]); \
        f2 s1 = *(const f2*)(lds + (RB) + 16384 + ro2[g2]); \
        f2 s2 = *(const f2*)(lds + (RB) + 32768 + ro2[g2]); \
        f2 s3 = *(const f2*)(lds + (RB) + 49152 + ro2[g2]); \
        gsv[g2] = (s0 + s1) + (s2 + s3); \
      } \
      float ig0 = 1.f / (1.f + __expf(-gsv[0][0])); \
      float fg0 = 1.f / (1.f + __expf(-gsv[1][0])); \
      float gg0 = 2.f / (1.f + __expf(-2.f * gsv[2][0])) - 1.f; \
      float og0 = 1.f / (1.f + __expf(-gsv[3][0])); \
      float cn0 = fg0 * (C0) + ig0 * gg0; \
      (C0) = cn0; \
      float th0 = 2.f / (1.f + __expf(-2.f * cn0)) - 1.f; \
      unsigned short* hp0 = (HDST) + (HB); \
      unsigned hv0 = f2h(og0 * th0); \
      asm volatile("global_store_short %0, %1, off sc0 sc1" :: "v"(hp0), "v"(hv0) : "memory"); \
      float ig1 = 1.f / (1.f + __expf(-gsv[0][1])); \
      float fg1 = 1.f / (1.f + __expf(-gsv[1][1])); \
      float gg1 = 2.f / (1.f + __expf(-2.f * gsv[2][1])) - 1.f; \
      float og1 = 1.f / (1.f + __expf(-gsv[3][1])); \
      float cn1 = fg1 * (C1) + ig1 * gg1; \
      (C1) = cn1; \
      float th1 = 2.f / (1.f + __expf(-2.f * cn1)) - 1.f; \
      unsigned short* hp1 = (HDST) + (HB) + 32; \
      unsigned hv1 = f2h(og1 * th1); \
      asm volatile("global_store_short %0, %1, off sc0 sc1" :: "v"(hp1), "v"(hv1) : "memory"); \
    } \
    __syncthreads(); /* drains h stores (vmcnt0, write-through ack) + exch reads + staging */ \
    if (tid == 0) \
      __hip_atomic_fetch_add(CNTP, 1, __ATOMIC_RELAXED, __HIP_MEMORY_SCOPE_AGENT); \
  } while (0)

  // ---- prologue: stage A(0) (h0 is zeroed; gate trivial) + x fragment ----
  STG_RING(h0 + gA * 32768, 0);
  {
    const unsigned short* xp = xT + (gA * 32 + l15) * 128 + xco;
    xa0 = *(const half8*)xp; xa1 = *(const half8*)(xp + 2048);
  }
  __syncthreads();   // drain prologue staging

#pragma unroll 1
  for (int t = 0; t < kSteps; t++) {
    const unsigned short* hsrc = (t & 1) ? h1 : h0;
    unsigned short* hdst = (t & 1) ? h0 : h1;

    // ---- A phase: compute A(t); poll B hidden under compute; stage B(t) under A's exchange ----
    SPIN_ISSUE(pollB, cntB);
    COMPUTE_ALL(0, xa0, xa1);
    SPIN_CHECK(pollB, cntB, 32 * t);          // gate B(t) staging; pre-exchange barrier
    STG_RING(hsrc + gB * 32768, 65536);
    {
      const unsigned short* xp = xT + (size_t)t * 65536 + (gB * 32 + l15) * 128 + xco;
      xb0 = *(const half8*)xp; xb1 = *(const half8*)(xp + 2048);
    }
    EXCHFIN(0, hdst, hbA, cA0, cA1, cntA);    // release A(t)

    // ---- B phase: compute B(t); poll A hidden under compute; stage A(t+1) under B's exchange ----
    SPIN_ISSUE(pollA, cntA);
    COMPUTE_ALL(65536, xb0, xb1);
    if (t + 1 < kSteps) {
      SPIN_CHECK(pollA, cntA, 32 * (t + 1));  // gate A(t+1) staging; pre-exchange barrier
      STG_RING(hdst + gA * 32768, 0);         // hsrc(t+1) = hdst(t)
      const unsigned short* xp = xT + (size_t)(t + 1) * 65536 + (gA * 32 + l15) * 128 + xco;
      xa0 = *(const half8*)xp; xa1 = *(const half8*)(xp + 2048);
    } else {
      if (tid == 0) asm volatile("s_waitcnt vmcnt(0)" ::: "memory");
      __syncthreads();                        // pre-exchange barrier only
    }
    EXCHFIN(65536, hdst, hbB, cB0, cB1, cntB);
  }
#undef EXCHFIN
#undef SPIN_CHECK
#undef SPIN_ISSUE
#undef COMPUTE_ALL
#undef CMP
#undef MFMA8
#undef STG_RING
#undef STG
}

// ---------- FC: out = h_last @ W_fc^T + b_fc ----------
__global__ void fc_kernel(const char* __restrict__ ws, const float* __restrict__ Wfc,
                          const float* __restrict__ bfc, float* __restrict__ out) {
  const unsigned short* h = (const unsigned short*)(ws + OFF_H1);  // t=254 writes h1
  int o = threadIdx.x & 127;
  int b = blockIdx.x * 2 + (threadIdx.x >> 7);
  const float* wrow = Wfc + (size_t)o * 1024;
  float acc = bfc[o];
  int gb = b >> 5, rb = b & 31;
#pragma unroll 4
  for (int k = 0; k < 1024; k += 8) {
    ushort8 hv = *(const ushort8*)&h[(((size_t)(gb * 32 + (k >> 5)) * 32 + rb) * 32) + (k & 31)];
    f4 w0 = *(const f4*)&wrow[k];
    f4 w1 = *(const f4*)&wrow[k + 4];
#pragma unroll
    for (int j = 0; j < 4; j++) acc += h2f(hv[j]) * w0[j];
#pragma unroll
    for (int j = 0; j < 4; j++) acc += h2f(hv[4 + j]) * w1[j];
  }
  out[(size_t)b * 128 + o] = acc;
}

extern "C" void kernel_launch(void* const* d_in, const int* in_sizes, int n_in,
                              void* d_out, int out_size, void* d_ws, size_t ws_size,
                              hipStream_t stream) {
  const float* x   = (const float*)d_in[0];
  const float* Wih = (const float*)d_in[1];
  const float* Whh = (const float*)d_in[2];
  const float* bih = (const float*)d_in[3];
  const float* bhh = (const float*)d_in[4];
  const float* Wfc = (const float*)d_in[5];
  const float* bfc = (const float*)d_in[6];
  char* ws = (char*)d_ws;

  hipMemsetAsync(ws + OFF_H0, 0, ((size_t)1 << 20) + 4096, stream);
  prep_wcat<<<2320, 256, 0, stream>>>(Wih, Whh, bih, bhh, ws);
  prep_xt<<<2048, 256, 0, stream>>>(x, ws);
  lstm_persist<<<256, 512, 0, stream>>>(ws);
  fc_kernel<<<256, 256, 0, stream>>>(ws, Wfc, bfc, (float*)d_out);
}

// Round 18
// 1825.105 us; speedup vs baseline: 1.0819x; 1.0819x over previous
//
#include <hip/hip_runtime.h>
#include <stdint.h>
#include <stddef.h>

typedef __attribute__((ext_vector_type(8))) _Float16 half8;
typedef __attribute__((ext_vector_type(8))) unsigned short ushort8;
typedef __attribute__((ext_vector_type(4))) float f4;
typedef __attribute__((ext_vector_type(2))) float f2;

#define AS1 __attribute__((address_space(1)))
#define AS3 __attribute__((address_space(3)))

namespace {
constexpr int kSteps = 255;   // reference iterates t = 0 .. T-2
constexpr int KTOT = 1152;    // 1024 (h) + 128 (x)

// workspace layout (bytes); total ~45 MB
// h layout: [group(16)][ub(32)][row(32)][u(32)] fp16 -> 2KB block slices
constexpr size_t OFF_H0   = 0;                                   // 1 MB  h ping
constexpr size_t OFF_CNT  = (size_t)1 << 20;                     // 4 KB  counters (16 x 64B)
constexpr size_t OFF_H1   = ((size_t)1 << 20) + 4096;            // 1 MB  h pong
constexpr size_t OFF_BSUM = OFF_H1 + ((size_t)1 << 20);          // 16 KB b_ih+b_hh (fp32)
constexpr size_t OFF_WCAT = OFF_BSUM + 16384;                    // 9.4 MB fp16 [4096][1152]
constexpr size_t OFF_XT   = OFF_WCAT + (size_t)4096 * KTOT * 2;  // 33.4 MB fp16 [255][512][128]
}

__device__ __forceinline__ unsigned short f2h(float f) {
  _Float16 h = (_Float16)f;
  return __builtin_bit_cast(unsigned short, h);
}
__device__ __forceinline__ float h2f(unsigned short s) {
  return (float)__builtin_bit_cast(_Float16, s);
}

// ---------- prep 1: Wcat fp16 + bsum ----------
__global__ void prep_wcat(const float* __restrict__ Wih, const float* __restrict__ Whh,
                          const float* __restrict__ bih, const float* __restrict__ bhh,
                          char* __restrict__ ws) {
  if (blockIdx.x < 2304) {
    unsigned gid = blockIdx.x * 256 + threadIdx.x;
    unsigned row = gid / 144, cc = gid % 144;
    const float* src = (cc < 128) ? (Whh + (size_t)row * 1024 + (size_t)cc * 8)
                                  : (Wih + (size_t)row * 128 + (size_t)(cc - 128) * 8);
    ushort8 o;
#pragma unroll
    for (int j = 0; j < 8; j++) o[j] = f2h(src[j]);
    *(ushort8*)((unsigned short*)(ws + OFF_WCAT) + (size_t)row * KTOT + cc * 8) = o;
  } else {
    int i = (blockIdx.x - 2304) * 256 + threadIdx.x;
    ((float*)(ws + OFF_BSUM))[i] = bih[i] + bhh[i];
  }
}

// ---------- prep 2: xT[t][b][i] = fp16(x[b][i][t]) ----------
__global__ void prep_xt(const float* __restrict__ x, char* __restrict__ ws) {
  unsigned short* xT = (unsigned short*)(ws + OFF_XT);
  __shared__ unsigned short tile[128][72];
  const int b = blockIdx.x >> 2;
  const int t0 = (blockIdx.x & 3) * 64;
  const int wv = threadIdx.x >> 6, tl = threadIdx.x & 63;
  if (t0 + tl < 255) {
#pragma unroll
    for (int ii = 0; ii < 32; ii++) {
      int i = wv + ii * 4;
      tile[i][tl] = f2h(x[((size_t)b * 128 + i) * 256 + t0 + tl]);
    }
  }
  __syncthreads();
  const int tl2 = threadIdx.x >> 4, ic = threadIdx.x & 15;
#pragma unroll
  for (int pp = 0; pp < 4; pp++) {
    int tloc = pp * 16 + tl2;
    int t = t0 + tloc;
    if (t < 255) {
      ushort8 v;
#pragma unroll
      for (int j = 0; j < 8; j++) v[j] = tile[ic * 8 + j][tloc];
      *(ushort8*)&xT[((size_t)t * 512 + b) * 128 + ic * 8] = v;
    }
  }
}

// ---------- persistent LSTM kernel: DUAL-CHAIN, cross-pipelined (r16 skeleton) ----------
// grid 256 = (bid&7) -> groups {g, g+8} (both on XCD g), bid>>3 -> 32-unit tile.
// Per iteration: COMPUTE A (0 barriers, ring A resident) -> spinB+sync (doubles as
// pre-exchange barrier) -> STAGE ring B (flies under A's exchange) -> EXCH A ->
// same for B (staging ring A for t+1). 6 barriers/iter, no WAITBARs, no piped poll
// (r17 lesson: an outstanding divergent VMEM poll forces vmcnt(0) at COMPUTE start).
// Bias folded into the x-MFMA (C = bias4) -> no acc-init movs.
// Coherence (r8/r15-proven, no inv): h stores write-through sc0 sc1; h loads SC0;
// relaxed release after vmcnt(0) drain.
__global__ __launch_bounds__(512) __attribute__((amdgpu_waves_per_eu(2, 2)))
void lstm_persist(char* __restrict__ ws) {
  const unsigned short* __restrict__ wcat = (const unsigned short*)(ws + OFF_WCAT);
  const float* __restrict__ bsum = (const float*)(ws + OFF_BSUM);
  const unsigned short* __restrict__ xT = (const unsigned short*)(ws + OFF_XT);
  unsigned short* h0 = (unsigned short*)(ws + OFF_H0);
  unsigned short* h1 = (unsigned short*)(ws + OFF_H1);

  __shared__ __align__(16) char lds[131072];   // 2 rings x (8 bufs x 8KB); exchange reuses ring

  const int tid = threadIdx.x;
  const int lane = tid & 63;
  const int w = tid >> 6;
  const int wk = w & 3;           // K slice (32 cols of each 128-col chunk)
  const int wn = w >> 2;          // N half (64 of 128 gate cols)
  const int l15 = lane & 15, l4 = lane >> 4;
  const int gA = blockIdx.x & 7;       // chain A group (XCD-aligned)
  const int gB = gA + 8;               // chain B group (same XCD)
  const int cblk = blockIdx.x >> 3;    // unit tile 0..31
  const int U0 = cblk * 32;
  int* cntA = (int*)(ws + OFF_CNT) + gA * 16;
  int* cntB = (int*)(ws + OFF_CNT) + gB * 16;

  // ---- weight fragments -> registers. col n = wn*64+nf*16+l15 = unit*4+gate ----
  half8 bf[9][4];   // 144 regs, shared by both chains
  f4 bias4[4];      // bias-fold C operand (16 regs, persistent)
#pragma unroll
  for (int nf = 0; nf < 4; nf++) {
    int u = wn * 16 + nf * 4 + (l15 >> 2);
    int R = (l15 & 3) * 1024 + U0 + u;          // PyTorch gate order i,f,g,o
    float b = bsum[R];
    float bs = (wk == 0) ? b : 0.f;             // 4-way K reduce: one slice seeds bias
    bias4[nf] = (f4){bs, bs, bs, bs};
#pragma unroll
    for (int c = 0; c < 9; c++)
      bf[c][nf] = *(const half8*)&wcat[(size_t)R * KTOT + c * 128 + wk * 32 + l4 * 8];
  }

  // ---- staging: chunk 8KB = 8 slots of 1KB; slot = w (1 load/wave/chunk) ----
  // LDS (row, c16) holds G(row, c16 ^ (row&7)); source pre-inverse-swizzled (rule #21).
  const int srow = w * 4 + (lane >> 4);          // 0..31
  const int scg = (lane & 15) ^ (srow & 7);
  const int hoff1 = (scg >> 2) * 1024 + srow * 32 + (scg & 3) * 8;   // + c*4096 per chunk
  // A ds_read: row = m*16+l15, c16 = (wk*4+l4) ^ (l15&7); a1 at +4096 (m=1)
  const int aBase = l15 * 256 + (((wk * 4 + l4) ^ (l15 & 7)) * 16);
  const int xco = (wk * 4 + l4) * 8;             // x direct-to-reg column (halves)

  // exchange constants. writer: n = wn*64+nf*16+l15 (0..127), rf = m*4+l4 (0..7)
  int nb8[4], hnw[4];
#pragma unroll
  for (int nf = 0; nf < 4; nf++) {
    int n = wn * 64 + nf * 16 + l15;
    nb8[nf] = n * 8;
    hnw[nf] = (n ^ (n >> 3)) & 7;
  }
  // reader: thread owns (unit uu, rows qr*4+hi*2 .. +1); float2 reads per slice
  const int uu = tid & 31;
  const int qr = (tid >> 5) & 7;
  const int hi = (tid >> 8) & 1;
  int ro2[4];
#pragma unroll
  for (int g2 = 0; g2 < 4; g2++) {
    int n = 4 * uu + g2;
    ro2[g2] = (n * 8 + (qr ^ ((n ^ (n >> 3)) & 7))) * 16 + hi * 8;
  }
  const size_t hbA = ((size_t)(gA * 32 + cblk) * 32 + (qr * 4 + hi * 2)) * 32 + uu;
  const size_t hbB = ((size_t)(gB * 32 + cblk) * 32 + (qr * 4 + hi * 2)) * 32 + uu;

  f4 acc[2][4];
  half8 xa0, xa1, xb0, xb1;                     // x fragments (global->reg, no LDS)
  float cA0 = 0.f, cA1 = 0.f, cB0 = 0.f, cB1 = 0.f;

#define STG(HS, C, RB, BUF) \
  __builtin_amdgcn_global_load_lds( \
      (const AS1 void*)((HS) + hoff1 + (C) * 4096), \
      (AS3 void*)(lds + (RB) + (BUF) * 8192 + w * 1024), 16, 0, 1)

#define STG_RING(HS, RB) do { \
    STG(HS, 0, RB, 0); STG(HS, 1, RB, 1); STG(HS, 2, RB, 2); STG(HS, 3, RB, 3); \
    STG(HS, 4, RB, 4); STG(HS, 5, RB, 5); STG(HS, 6, RB, 6); STG(HS, 7, RB, 7); \
  } while (0)

#define MFMA8(A0, A1, C) do { \
    acc[0][0] = __builtin_amdgcn_mfma_f32_16x16x32_f16(A0, bf[C][0], acc[0][0], 0, 0, 0); \
    acc[0][1] = __builtin_amdgcn_mfma_f32_16x16x32_f16(A0, bf[C][1], acc[0][1], 0, 0, 0); \
    acc[0][2] = __builtin_amdgcn_mfma_f32_16x16x32_f16(A0, bf[C][2], acc[0][2], 0, 0, 0); \
    acc[0][3] = __builtin_amdgcn_mfma_f32_16x16x32_f16(A0, bf[C][3], acc[0][3], 0, 0, 0); \
    acc[1][0] = __builtin_amdgcn_mfma_f32_16x16x32_f16(A1, bf[C][0], acc[1][0], 0, 0, 0); \
    acc[1][1] = __builtin_amdgcn_mfma_f32_16x16x32_f16(A1, bf[C][1], acc[1][1], 0, 0, 0); \
    acc[1][2] = __builtin_amdgcn_mfma_f32_16x16x32_f16(A1, bf[C][2], acc[1][2], 0, 0, 0); \
    acc[1][3] = __builtin_amdgcn_mfma_f32_16x16x32_f16(A1, bf[C][3], acc[1][3], 0, 0, 0); \
  } while (0)

#define CMP(C, RB) do { \
    const char* _b = lds + (RB) + (C) * 8192 + aBase; \
    half8 a0 = *(const half8*)(_b); \
    half8 a1 = *(const half8*)(_b + 4096); \
    MFMA8(a0, a1, C); \
  } while (0)

// first MFMA writes acc = x*Wx + bias (no acc-init movs)
#define COMPUTE_ALL(RB, XA0, XA1) do { \
    _Pragma("unroll") \
    for (int nf = 0; nf < 4; nf++) { \
      acc[0][nf] = __builtin_amdgcn_mfma_f32_16x16x32_f16(XA0, bf[8][nf], bias4[nf], 0, 0, 0); \
      acc[1][nf] = __builtin_amdgcn_mfma_f32_16x16x32_f16(XA1, bf[8][nf], bias4[nf], 0, 0, 0); \
    } \
    CMP(0, RB); CMP(1, RB); CMP(2, RB); CMP(3, RB); \
    CMP(4, RB); CMP(5, RB); CMP(6, RB); CMP(7, RB); \
  } while (0)

// blocking spin (r16-proven): poll only inside the join, nothing outstanding in COMPUTE
#define SPIN(CNTP, TGT) do { \
    if (tid == 0) { \
      int guard = 1 << 18; \
      while (guard--) { \
        int c; \
        asm volatile("global_load_dword %0, %1, off sc0 sc1\n\ts_waitcnt vmcnt(0)" \
                     : "=v"(c) : "v"(CNTP) : "memory"); \
        if (c >= (TGT)) break; \
        __builtin_amdgcn_s_sleep(1); \
      } \
    } \
    __syncthreads(); /* joins; also = pre-exchange barrier (compute reads drained) */ \
  } while (0)

// exchange (in own ring) + activation + h store + release; 2 barriers
#define EXCHFIN(RB, HDST, HB, C0, C1, CNTP) do { \
    _Pragma("unroll") \
    for (int m = 0; m < 2; m++) \
      _Pragma("unroll") \
      for (int nf = 0; nf < 4; nf++) { \
        int rf = m * 4 + l4; \
        *(f4*)(lds + (RB) + wk * 16384 + (size_t)(nb8[nf] + (rf ^ hnw[nf])) * 16) = acc[m][nf]; \
      } \
    __syncthreads(); \
    { \
      f2 gsv[4]; \
      _Pragma("unroll") \
      for (int g2 = 0; g2 < 4; g2++) { \
        f2 s0 = *(const f2*)(lds + (RB) + ro2[g2]); \
        f2 s1 = *(const f2*)(lds + (RB) + 16384 + ro2[g2]); \
        f2 s2 = *(const f2*)(lds + (RB) + 32768 + ro2[g2]); \
        f2 s3 = *(const f2*)(lds + (RB) + 49152 + ro2[g2]); \
        gsv[g2] = (s0 + s1) + (s2 + s3); \
      } \
      float ig0 = 1.f / (1.f + __expf(-gsv[0][0])); \
      float fg0 = 1.f / (1.f + __expf(-gsv[1][0])); \
      float gg0 = 2.f / (1.f + __expf(-2.f * gsv[2][0])) - 1.f; \
      float og0 = 1.f / (1.f + __expf(-gsv[3][0])); \
      float cn0 = fg0 * (C0) + ig0 * gg0; \
      (C0) = cn0; \
      float th0 = 2.f / (1.f + __expf(-2.f * cn0)) - 1.f; \
      unsigned short* hp0 = (HDST) + (HB); \
      unsigned hv0 = f2h(og0 * th0); \
      asm volatile("global_store_short %0, %1, off sc0 sc1" :: "v"(hp0), "v"(hv0) : "memory"); \
      float ig1 = 1.f / (1.f + __expf(-gsv[0][1])); \
      float fg1 = 1.f / (1.f + __expf(-gsv[1][1])); \
      float gg1 = 2.f / (1.f + __expf(-2.f * gsv[2][1])) - 1.f; \
      float og1 = 1.f / (1.f + __expf(-gsv[3][1])); \
      float cn1 = fg1 * (C1) + ig1 * gg1; \
      (C1) = cn1; \
      float th1 = 2.f / (1.f + __expf(-2.f * cn1)) - 1.f; \
      unsigned short* hp1 = (HDST) + (HB) + 32; \
      unsigned hv1 = f2h(og1 * th1); \
      asm volatile("global_store_short %0, %1, off sc0 sc1" :: "v"(hp1), "v"(hv1) : "memory"); \
    } \
    __syncthreads(); /* drains h stores (vmcnt0, write-through ack) + exch reads + staging */ \
    if (tid == 0) \
      __hip_atomic_fetch_add(CNTP, 1, __ATOMIC_RELAXED, __HIP_MEMORY_SCOPE_AGENT); \
  } while (0)

  // ---- prologue: stage A(0) (h0 is zeroed; gate trivial) + x fragment ----
  STG_RING(h0 + gA * 32768, 0);
  {
    const unsigned short* xp = xT + (gA * 32 + l15) * 128 + xco;
    xa0 = *(const half8*)xp; xa1 = *(const half8*)(xp + 2048);
  }
  __syncthreads();   // drain prologue staging

#pragma unroll 1
  for (int t = 0; t < kSteps; t++) {
    const unsigned short* hsrc = (t & 1) ? h1 : h0;
    unsigned short* hdst = (t & 1) ? h0 : h1;

    // ---- A phase: compute A(t); stage B(t) under A's exchange ----
    COMPUTE_ALL(0, xa0, xa1);
    SPIN(cntB, 32 * t);                       // gate B(t) staging; pre-exchange barrier
    STG_RING(hsrc + gB * 32768, 65536);
    {
      const unsigned short* xp = xT + (size_t)t * 65536 + (gB * 32 + l15) * 128 + xco;
      xb0 = *(const half8*)xp; xb1 = *(const half8*)(xp + 2048);
    }
    EXCHFIN(0, hdst, hbA, cA0, cA1, cntA);    // release A(t)

    // ---- B phase: compute B(t); stage A(t+1) under B's exchange ----
    COMPUTE_ALL(65536, xb0, xb1);
    if (t + 1 < kSteps) {
      SPIN(cntA, 32 * (t + 1));               // gate A(t+1) staging; pre-exchange barrier
      STG_RING(hdst + gA * 32768, 0);         // hsrc(t+1) = hdst(t)
      const unsigned short* xp = xT + (size_t)(t + 1) * 65536 + (gA * 32 + l15) * 128 + xco;
      xa0 = *(const half8*)xp; xa1 = *(const half8*)(xp + 2048);
    } else {
      __syncthreads();                        // pre-exchange barrier only
    }
    EXCHFIN(65536, hdst, hbB, cB0, cB1, cntB);
  }
#undef EXCHFIN
#undef SPIN
#undef COMPUTE_ALL
#undef CMP
#undef MFMA8
#undef STG_RING
#undef STG
}

// ---------- FC: out = h_last @ W_fc^T + b_fc ----------
__global__ void fc_kernel(const char* __restrict__ ws, const float* __restrict__ Wfc,
                          const float* __restrict__ bfc, float* __restrict__ out) {
  const unsigned short* h = (const unsigned short*)(ws + OFF_H1);  // t=254 writes h1
  int o = threadIdx.x & 127;
  int b = blockIdx.x * 2 + (threadIdx.x >> 7);
  const float* wrow = Wfc + (size_t)o * 1024;
  float acc = bfc[o];
  int gb = b >> 5, rb = b & 31;
#pragma unroll 4
  for (int k = 0; k < 1024; k += 8) {
    ushort8 hv = *(const ushort8*)&h[(((size_t)(gb * 32 + (k >> 5)) * 32 + rb) * 32) + (k & 31)];
    f4 w0 = *(const f4*)&wrow[k];
    f4 w1 = *(const f4*)&wrow[k + 4];
#pragma unroll
    for (int j = 0; j < 4; j++) acc += h2f(hv[j]) * w0[j];
#pragma unroll
    for (int j = 0; j < 4; j++) acc += h2f(hv[4 + j]) * w1[j];
  }
  out[(size_t)b * 128 + o] = acc;
}

extern "C" void kernel_launch(void* const* d_in, const int* in_sizes, int n_in,
                              void* d_out, int out_size, void* d_ws, size_t ws_size,
                              hipStream_t stream) {
  const float* x   = (const float*)d_in[0];
  const float* Wih = (const float*)d_in[1];
  const float* Whh = (const float*)d_in[2];
  const float* bih = (const float*)d_in[3];
  const float* bhh = (const float*)d_in[4];
  const float* Wfc = (const float*)d_in[5];
  const float* bfc = (const float*)d_in[6];
  char* ws = (char*)d_ws;

  hipMemsetAsync(ws + OFF_H0, 0, ((size_t)1 << 20) + 4096, stream);
  prep_wcat<<<2320, 256, 0, stream>>>(Wih, Whh, bih, bhh, ws);
  prep_xt<<<2048, 256, 0, stream>>>(x, ws);
  lstm_persist<<<256, 512, 0, stream>>>(ws);
  fc_kernel<<<256, 256, 0, stream>>>(ws, Wfc, bfc, (float*)d_out);
}